// Round 7
// baseline (155.622 us; speedup 1.0000x reference)
//
#include <hip/hip_runtime.h>
#include <cstddef>

#define NN 4096   // nodes
#define NL 8      // layers
#define ND 128    // feature dim

#define CHUNK 16            // j's per block
#define MAXS  CHUNK         // max distinct srcs per chunk

typedef int   int4v   __attribute__((ext_vector_type(4)));
typedef float float4v __attribute__((ext_vector_type(4)));

// ---------------------------------------------------------------------------
// Fully fused: ONE kernel, 2048 blocks = 8 layers x 256 chunks of 16 j's.
// Per block:
//   1. src scan for its 16 j's (descending 16-row rounds, early exit; top
//      rows are L2-hot since all 256 blocks of a layer read them)
//   2. row sums (deg) for its 16 chunk rows + its <=16 distinct src rows
//      (chunk rows are the exclusive 512MB stream; src rows L2-hot)
//   3. GEMV Wf = W @ feature[src] for distinct srcs only (W reads L1/L2-hot,
//      fb reads are LDS broadcasts)
//   4. scale + nontemporal coalesced stores of 16 output rows
// No second launch, no global sync, no workspace: each block's compute
// overlaps every other block's HBM streaming.
// ---------------------------------------------------------------------------
__global__ __launch_bounds__(256) void fused_kernel(
    const float* __restrict__ feature, const float* __restrict__ W,
    const int* __restrict__ adj, float* __restrict__ out) {
  __shared__ int   s_cand[16][CHUNK];
  __shared__ int   s_src[CHUNK];
  __shared__ int   s_fnd[CHUNK];
  __shared__ int   s_list[MAXS];
  __shared__ int   s_smap[CHUNK];
  __shared__ int   s_nb;
  __shared__ float s_deg[CHUNK + MAXS];
  __shared__ float s_scj[CHUNK];
  __shared__ float s_fb[MAXS][ND];
  __shared__ float s_wf[MAXS][ND];

  const int t = threadIdx.x;
  const int l = blockIdx.x & 7;
  const int jbase = (blockIdx.x >> 3) * CHUNK;
  const int* __restrict__ Al = adj + (size_t)l * NN * NN;

  // ---- phase 1: src scan (16 i's per round, all 16 j's in parallel) ----
  const int ii = t >> 4;          // 0..15 : row offset within round
  const int jj = t & 15;          // 0..15 : which j
  const int j = jbase + jj;
  if (t < CHUNK) { s_fnd[t] = 0; s_src[t] = jbase + t; }
  if (t == 0) s_nb = 0;
  __syncthreads();

  int itop = NN - 1;
  while (true) {
    const int i = itop - ii;
    int a = (i > j && i >= 0) ? Al[(size_t)i * NN + j] : 0;
    s_cand[ii][jj] = (a != 0) ? i : -1;
    __syncthreads();
    if (t < CHUNK && !s_fnd[t]) {
      int best = -1;
#pragma unroll
      for (int k = 0; k < 16; ++k) best = max(best, s_cand[k][t]);
      if (best >= 0) { s_src[t] = best; s_fnd[t] = 1; }
    }
    const bool mydone =
        (t >= CHUNK) || s_fnd[t] || (itop - 16 <= jbase + t);
    itop -= 16;
    if (__syncthreads_and((int)mydone)) break;
    if (itop < 0) break;
  }
  __syncthreads();

  // ---- phase 2: distinct-src list + slot map (first-occurrence order) ----
  if (t < CHUNK) {
    const int s = s_src[t];
    int first = 0;
    while (s_src[first] != s) ++first;
    int slot = 0;
    for (int r = 0; r < first; ++r) {
      bool isf = true;
      for (int q = 0; q < r; ++q)
        if (s_src[q] == s_src[r]) { isf = false; break; }
      slot += isf;
    }
    s_smap[t] = slot;
    if (first == t) { s_list[slot] = s; atomicAdd(&s_nb, 1); }
  }
  __syncthreads();
  const int nb = s_nb;

  // ---- phase 3: row sums for 16 chunk rows + nb src rows ----
  {
    const int w = t >> 6;       // wave 0..3
    const int lane = t & 63;
    const int nrows = CHUNK + nb;
    for (int r = w; r < nrows; r += 4) {
      const int row = (r < CHUNK) ? (jbase + r) : s_list[r - CHUNK];
      const int4v* __restrict__ p =
          reinterpret_cast<const int4v*>(Al + (size_t)row * NN);
      int s = 0;
#pragma unroll
      for (int k = 0; k < 16; ++k) {
        int4v v = __builtin_nontemporal_load(&p[lane + k * 64]);
        s += v.x + v.y + v.z + v.w;
      }
      for (int off = 32; off > 0; off >>= 1) s += __shfl_down(s, off, 64);
      if (lane == 0) s_deg[r] = (float)s + 1.0f;
    }
  }
  // stage feature rows for the distinct srcs (independent of row sums)
  for (int idx = t; idx < nb * 32; idx += 256) {
    const int k = idx >> 5, q = idx & 31;
    const int i = s_list[k];
    reinterpret_cast<float4v*>(s_fb[k])[q] =
        reinterpret_cast<const float4v*>(feature + ((size_t)i * NL + l) * ND)[q];
  }
  __syncthreads();

  // ---- phase 4: scales + GEMV ----
  if (t < CHUNK)
    s_scj[t] = rsqrtf(s_deg[CHUNK + s_smap[t]] * s_deg[t]);

  {
    const int d = t & 127;
    const int h = t >> 7;
    const float4v* __restrict__ Wd =
        reinterpret_cast<const float4v*>(W + (size_t)d * ND);
#pragma unroll 1
    for (int kk = 0; kk < 8; ++kk) {
      const int k = h + 2 * kk;
      if (k >= nb) break;
      float4v a4 = {0.f, 0.f, 0.f, 0.f};
#pragma unroll
      for (int q = 0; q < 32; ++q) {
        const float4v wq = Wd[q];
        const float4v fq = reinterpret_cast<const float4v*>(s_fb[k])[q];
        a4.x += wq.x * fq.x; a4.y += wq.y * fq.y;
        a4.z += wq.z * fq.z; a4.w += wq.w * fq.w;
      }
      s_wf[k][d] = a4.x + a4.y + a4.z + a4.w;
    }
  }
  __syncthreads();

  // ---- phase 5: scaled coalesced NT stores ----
  for (int idx = t; idx < CHUNK * 32; idx += 256) {
    const int r = idx >> 5, q = idx & 31;
    const int sl = s_smap[r];
    const float sc = s_scj[r];
    float4v v = reinterpret_cast<const float4v*>(s_wf[sl])[q];
    v.x *= sc; v.y *= sc; v.z *= sc; v.w *= sc;
    __builtin_nontemporal_store(
        v, reinterpret_cast<float4v*>(out) +
               ((size_t)(jbase + r) * NL + l) * 32 + q);
  }
}

// ---------------------------------------------------------------------------
extern "C" void kernel_launch(void* const* d_in, const int* in_sizes, int n_in,
                              void* d_out, int out_size, void* d_ws,
                              size_t ws_size, hipStream_t stream) {
  const float* feature = (const float*)d_in[0];   // [NN, NL, ND] f32
  const float* W       = (const float*)d_in[1];   // [ND, ND]     f32
  const int*   adj     = (const int*)d_in[2];     // [NL, NN, NN] i32
  float* out = (float*)d_out;                     // [NN, NL, ND] f32

  fused_kernel<<<NL * (NN / CHUNK), 256, 0, stream>>>(feature, W, adj, out);
}